// Round 19
// baseline (478.362 us; speedup 1.0000x reference)
//
#include <hip/hip_runtime.h>
#include <hip/hip_bf16.h>

#define H_DIM 2048
#define I_DIM 768
#define NEXP 64
#define TOPK 8
#define NTOK 1024   // B*S
#define BM 256      // token tile (count ~128+-11 => single chunk)
#define BKS 32      // K per step

typedef float f32x4 __attribute__((ext_vector_type(4)));
typedef unsigned int u32x4 __attribute__((ext_vector_type(4)));
typedef unsigned int u32x2 __attribute__((ext_vector_type(2)));
typedef short bf16v8 __attribute__((ext_vector_type(8)));   // 8 bf16 in 4 VGPRs
typedef unsigned short u16x8 __attribute__((ext_vector_type(8)));
typedef unsigned int u32;

// ---------------- workspace layout (bytes) ----------------
// topk_idx : int   [NTOK*TOPK]           @ 0
// topk_w   : float [NTOK*TOPK]           @ 32768
// counts   : int   [NEXP]                @ 65536
// offsets  : int   [NEXP]                @ 65792
// lists    : int   [NEXP*NTOK]           @ 66048    (ends 328192)
// wlist    : float [NEXP*NTOK]           @ 328192   (ends 590336)
// inv      : int   [NTOK*TOPK]           @ 590336   (ends 623104)
// hmid     : bf16  [NTOK*TOPK * I_DIM]   @ 623104   (ends 13206016)
// xbf      : bf16  [NTOK * H_DIM]        @ 13206016 (ends 17400320)
// part     : bf16  [NTOK*TOPK * H_DIM]   @ 17400320 (ends 50954752)
#define WS_NEEDED 50954752ull

__device__ inline unsigned short f2bf(float f) {
    union { float f; u32 u; } v; v.f = f;
    u32 r = (v.u + 0x7FFFu + ((v.u >> 16) & 1u)) >> 16;
    return (unsigned short)r;
}
__device__ inline u32 pack2(float a, float b) {
    return (u32)f2bf(a) | ((u32)f2bf(b) << 16);
}

__global__ void zero_kernel(float4* p, int n4) {
    int i = blockIdx.x * blockDim.x + threadIdx.x;
    if (i < n4) p[i] = (float4){0.f, 0.f, 0.f, 0.f};
}

// one block per token, 512 threads: fused x->bf16 conversion + 8-way-K router
__global__ __launch_bounds__(512) void router_kernel(
    const float* __restrict__ x, const float* __restrict__ Wr,
    int* __restrict__ topk_idx, float* __restrict__ topk_w,
    ushort4* __restrict__ xbf)
{
    const int t   = blockIdx.x;
    const int tid = threadIdx.x;
    const int lane = tid & 63;
    const int wv   = tid >> 6;           // 0..7 -> K chunk of 256
    __shared__ float xs[H_DIM];
    __shared__ float red[8][64];

    const float* xrow = x + (size_t)t * H_DIM;
    {
        const float4* src = (const float4*)xrow;
        float4 v = src[tid];             // 512 threads x float4 = 2048 floats
        ((float4*)xs)[tid] = v;
        ushort4 o;
        o.x = f2bf(v.x); o.y = f2bf(v.y); o.z = f2bf(v.z); o.w = f2bf(v.w);
        xbf[(size_t)t * (H_DIM / 4) + tid] = o;   // fused bf16 copy
    }
    __syncthreads();

    float acc = 0.f;
    const int h0 = wv * 256;
    #pragma unroll 8
    for (int h = h0; h < h0 + 256; ++h) acc += xs[h] * Wr[(size_t)h * NEXP + lane];
    red[wv][lane] = acc;
    __syncthreads();

    if (tid < 64) {
        const int e = tid;
        float logit = ((red[0][e] + red[1][e]) + (red[2][e] + red[3][e]))
                    + ((red[4][e] + red[5][e]) + (red[6][e] + red[7][e]));

        float m = logit;
        #pragma unroll
        for (int o = 32; o > 0; o >>= 1) m = fmaxf(m, __shfl_xor(m, o));
        float p = __expf(logit - m);
        float s = p;
        #pragma unroll
        for (int o = 32; o > 0; o >>= 1) s += __shfl_xor(s, o);
        float prob = p / s;

        float myp = prob;
        float kw[TOPK]; int kid[TOPK]; float wsum = 0.f;
        #pragma unroll
        for (int k = 0; k < TOPK; ++k) {
            float v = myp; int bi = e;
            #pragma unroll
            for (int o = 32; o > 0; o >>= 1) {
                float ov = __shfl_xor(v, o);
                int   oi = __shfl_xor(bi, o);
                if (ov > v || (ov == v && oi < bi)) { v = ov; bi = oi; }
            }
            kw[k] = v; kid[k] = bi; wsum += v;
            if (e == bi) myp = -1.f;
        }
        if (e == 0) {
            float inv = 1.f / wsum;
            #pragma unroll
            for (int k = 0; k < TOPK; ++k) {
                topk_idx[t * TOPK + k] = kid[k];
                topk_w[t * TOPK + k]   = kw[k] * inv;
            }
        }
    }
}

// one wave per expert; deterministic ordered compaction + inverse rank map
__global__ __launch_bounds__(64) void listbuild_kernel(
    const int* __restrict__ topk_idx, const float* __restrict__ topk_w,
    int* __restrict__ counts, int* __restrict__ lists, float* __restrict__ wlist,
    int* __restrict__ invmap)
{
    const int e = blockIdx.x;
    const int lane = threadIdx.x;
    int n = 0;
    for (int base = 0; base < NTOK * TOPK; base += 64) {
        int s = base + lane;
        int idx = topk_idx[s];
        bool match = (idx == e);
        unsigned long long mask = __ballot(match);
        int pre = __popcll(mask & ((1ull << lane) - 1ull));
        if (match) {
            lists[e * NTOK + n + pre] = s >> 3;
            wlist[e * NTOK + n + pre] = topk_w[s];
            invmap[s] = n + pre;
        }
        n += __popcll(mask);
    }
    if (lane == 0) counts[e] = n;
}

__global__ __launch_bounds__(64) void scan_kernel(
    const int* __restrict__ counts, int* __restrict__ offsets)
{
    int e = threadIdx.x;
    int v = counts[e];
    int xacc = v;
    #pragma unroll
    for (int o = 1; o < 64; o <<= 1) {
        int y = __shfl_up(xacc, o);
        if (e >= o) xacc += y;
    }
    offsets[e] = xacc - v;
}

#define MFMA_BF16 __builtin_amdgcn_mfma_f32_16x16x32_bf16
#define LGKM0()  asm volatile("s_waitcnt lgkmcnt(0)" ::: "memory")
#define RAWBAR() __builtin_amdgcn_s_barrier()

// ---------------- MFMA gate+up: grid 1536 (xcd-swizzled), block 512, BN=32 ----------------
// R18 core, NT hint removed from weight loads (let L2 retain shared rows)
__global__ __launch_bounds__(512, 4) void gateup_kernel(
    const unsigned short* __restrict__ xbf,
    const float* __restrict__ Wg, const float* __restrict__ Wu,
    const int* __restrict__ counts, const int* __restrict__ offsets,
    const int* __restrict__ lists, const float* __restrict__ wlist,
    unsigned short* __restrict__ hmid)
{
    const int b  = blockIdx.x;
    const int wg = (b & 7) * 192 + (b >> 3);
    const int itile = wg % 24;
    const int e     = wg / 24;

    const int count = counts[e];
    if (count == 0) return;
    const int off = offsets[e];
    const int i0 = itile * 32;

    __shared__ unsigned short Alds[2][BM][40];   // 40960 B
    __shared__ u32 Bgl[2][32 * 20];              // 5120 B
    __shared__ u32 Bul[2][32 * 20];              // 5120 B

    const int tid  = threadIdx.x;
    const int lane = tid & 63;
    const int wid  = tid >> 6;
    const int wm   = wid >> 1, wn = wid & 1;
    const int kb   = lane >> 4;
    const int l15  = lane & 15;

    const int ar = tid >> 1;
    const int ah = (tid & 1) * 16;
    const int bnn  = tid & 31;
    const int bkq  = (tid >> 5) & 7;
    const int bmat = tid >> 8;
    const float* WB = (bmat ? Wu : Wg) + (size_t)e * H_DIM * I_DIM + i0 + bnn;
    const int key4w = 4 * ((bnn >> 3) & 3);
    const int bwoff = bnn * 20 + ((2 * bkq) ^ key4w);
    const int brn   = wn * 16 + l15;
    const int key4r = 4 * ((brn >> 3) & 3);

    for (int mstart = 0; mstart < count; mstart += BM) {
        const int pr = mstart + ar;
        const bool aact = pr < count;
        const unsigned short* xrow = xbf + (size_t)(aact ? lists[e * NTOK + pr] : 0) * H_DIM + ah;
        const bool mact = (mstart + wm * 64) < count;

        f32x4 accg[4], accu[4];
        #pragma unroll
        for (int i = 0; i < 4; ++i) {
            accg[i] = (f32x4){0.f, 0.f, 0.f, 0.f};
            accu[i] = (f32x4){0.f, 0.f, 0.f, 0.f};
        }

        u32x4 aA0, aA1, aB0, aB1;                 // A prefetch, 2 sets
        float bA0, bA1, bA2, bA3;                 // B prefetch set A
        float bB0, bB1, bB2, bB3;                 // B prefetch set B

#define GU_LOADA(P0,P1,h)                                                       \
        if (aact) {                                                             \
            const u32x4* pa_ = (const u32x4*)(xrow + (h));                      \
            P0 = pa_[0]; P1 = pa_[1];                                           \
        }
#define GU_LOADB(R0,R1,R2,R3,h)                                                 \
        {                                                                       \
            R0 = WB[(size_t)((h) + 4 * bkq)     * I_DIM];                       \
            R1 = WB[(size_t)((h) + 4 * bkq + 1) * I_DIM];                       \
            R2 = WB[(size_t)((h) + 4 * bkq + 2) * I_DIM];                       \
            R3 = WB[(size_t)((h) + 4 * bkq + 3) * I_DIM];                       \
        }
#define GU_STORE(BUF,P0,P1,R0,R1,R2,R3)                                         \
        if (aact) {                                                             \
            *(u32x4*)&Alds[BUF][ar][ah]     = P0;                               \
            *(u32x4*)&Alds[BUF][ar][ah + 8] = P1;                               \
        }                                                                       \
        {                                                                       \
            u32x2 w_; w_.x = pack2(R0, R1); w_.y = pack2(R2, R3);               \
            *(u32x2*)((bmat ? Bul[BUF] : Bgl[BUF]) + bwoff) = w_;               \
        }
#define GU_MFMA(BUF)                                                            \
        if (mact) {                                                             \
            bf16v8 af[4], bg, bu;                                               \
            _Pragma("unroll")                                                   \
            for (int mf = 0; mf < 4; ++mf)                                      \
                af[mf] = *(const bf16v8*)&Alds[BUF][wm * 64 + mf * 16 + l15][kb * 8]; \
            bg = *(const bf16v8*)&Bgl[BUF][brn * 20 + ((4 * kb) ^ key4r)];      \
            bu = *(const bf16v8*)&Bul[BUF][brn * 20 + ((4 * kb) ^ key4r)];      \
            _Pragma("unroll")                                                   \
            for (int mf = 0; mf < 4; ++mf) {                                    \
                accg[mf] = MFMA_BF16(af[mf], bg, accg[mf], 0, 0, 0);            \
                accu[mf] = MFMA_BF16(af[mf], bu, accu[mf], 0, 0, 0);            \
            }                                                                   \
        }
#define GU_PHASE(BUF,P0,P1,R0,R1,R2,R3,nh)                                      \
        GU_STORE(BUF, P0, P1, R0, R1, R2, R3);                                  \
        if ((nh) < H_DIM) { GU_LOADB(R0, R1, R2, R3, (nh)); GU_LOADA(P0, P1, (nh)); } \
        LGKM0();                                                                \
        RAWBAR();                                                               \
        __builtin_amdgcn_s_setprio(1);                                          \
        GU_MFMA(BUF);                                                           \
        __builtin_amdgcn_s_setprio(0);

        GU_LOADB(bA0, bA1, bA2, bA3, 0);    GU_LOADA(aA0, aA1, 0);
        GU_LOADB(bB0, bB1, bB2, bB3, BKS);  GU_LOADA(aB0, aB1, BKS);

        for (int hh = 0; hh < H_DIM; hh += 2 * BKS) {
            GU_PHASE(0, aA0, aA1, bA0, bA1, bA2, bA3, hh + 2 * BKS);
            GU_PHASE(1, aB0, aB1, bB0, bB1, bB2, bB3, hh + 3 * BKS);
        }
        __syncthreads();
#undef GU_LOADA
#undef GU_LOADB
#undef GU_STORE
#undef GU_MFMA
#undef GU_PHASE

        if (mact) {
            #pragma unroll
            for (int mf = 0; mf < 4; ++mf)
                #pragma unroll
                for (int r = 0; r < 4; ++r) {
                    int pos = mstart + wm * 64 + mf * 16 + kb * 4 + r;
                    if (pos < count) {
                        float wgt = wlist[e * NTOK + pos];
                        float g = accg[mf][r], u = accu[mf][r];
                        float s = 1.f / (1.f + __expf(-g));
                        hmid[(size_t)(off + pos) * I_DIM + i0 + wn * 16 + l15] = f2bf(g * s * u * wgt);
                    }
                }
        }
    }
}

// ---------------- MFMA down: grid 4096 (xcd-swizzled), block 512, BN=32 ----------------
template <bool USE_PART>
__global__ __launch_bounds__(512, 4) void down_kernel(
    const unsigned short* __restrict__ hmid, const float* __restrict__ Wd,
    const int* __restrict__ counts, const int* __restrict__ offsets,
    const int* __restrict__ lists, float* __restrict__ out,
    unsigned short* __restrict__ part)
{
    const int b  = blockIdx.x;
    const int wg = (b & 7) * 512 + (b >> 3);
    const int htile = wg % 64;
    const int e     = wg / 64;

    const int count = counts[e];
    if (count == 0) return;
    const int off = offsets[e];
    const int h0 = htile * 32;

    __shared__ unsigned short Alds[2][BM][40];   // 40960 B
    __shared__ u32 Bdl[2][32 * 20];              // 5120 B

    const int tid  = threadIdx.x;
    const int lane = tid & 63;
    const int wid  = tid >> 6;
    const int wm   = wid >> 1, wn = wid & 1;
    const int kb   = lane >> 4;
    const int l15  = lane & 15;

    const int ar = tid >> 1;
    const int ah = (tid & 1) * 16;
    const int bnn  = tid & 31;
    const int bkq  = (tid >> 5) & 7;
    const bool bact = tid < 256;
    const float* WB = Wd + (size_t)e * I_DIM * H_DIM + h0 + bnn;
    const int key4w = 4 * ((bnn >> 3) & 3);
    const int bwoff = bnn * 20 + ((2 * bkq) ^ key4w);
    const int brn   = wn * 16 + l15;
    const int key4r = 4 * ((brn >> 3) & 3);

    for (int mstart = 0; mstart < count; mstart += BM) {
        const int pr = mstart + ar;
        const bool aact = pr < count;
        const unsigned short* hrow = hmid + (size_t)(off + (aact ? pr : 0)) * I_DIM + ah;
        const bool mact = (mstart + wm * 64) < count;

        f32x4 acc[4];
        #pragma unroll
        for (int i = 0; i < 4; ++i) acc[i] = (f32x4){0.f, 0.f, 0.f, 0.f};

        u32x4 aA0, aA1, aB0, aB1;
        float bA0, bA1, bA2, bA3;
        float bB0, bB1, bB2, bB3;

#define DN_LOADA(P0,P1,k)                                                       \
        if (aact) {                                                             \
            const u32x4* p_ = (const u32x4*)(hrow + (k));                       \
            P0 = p_[0]; P1 = p_[1];                                             \
        }
#define DN_LOADB(R0,R1,R2,R3,k)                                                 \
        if (bact) {                                                             \
            R0 = WB[(size_t)((k) + 4 * bkq)     * H_DIM];                       \
            R1 = WB[(size_t)((k) + 4 * bkq + 1) * H_DIM];                       \
            R2 = WB[(size_t)((k) + 4 * bkq + 2) * H_DIM];                       \
            R3 = WB[(size_t)((k) + 4 * bkq + 3) * H_DIM];                       \
        }
#define DN_STORE(BUF,P0,P1,R0,R1,R2,R3)                                         \
        if (aact) {                                                             \
            *(u32x4*)&Alds[BUF][ar][ah]     = P0;                               \
            *(u32x4*)&Alds[BUF][ar][ah + 8] = P1;                               \
        }                                                                       \
        if (bact) {                                                             \
            u32x2 w_; w_.x = pack2(R0, R1); w_.y = pack2(R2, R3);               \
            *(u32x2*)(Bdl[BUF] + bwoff) = w_;                                   \
        }
#define DN_MFMA(BUF)                                                            \
        if (mact) {                                                             \
            bf16v8 af[4], bd;                                                   \
            _Pragma("unroll")                                                   \
            for (int mf = 0; mf < 4; ++mf)                                      \
                af[mf] = *(const bf16v8*)&Alds[BUF][wm * 64 + mf * 16 + l15][kb * 8]; \
            bd = *(const bf16v8*)&Bdl[BUF][brn * 20 + ((4 * kb) ^ key4r)];      \
            _Pragma("unroll")                                                   \
            for (int mf = 0; mf < 4; ++mf)                                      \
                acc[mf] = MFMA_BF16(af[mf], bd, acc[mf], 0, 0, 0);              \
        }
#define DN_PHASE(BUF,P0,P1,R0,R1,R2,R3,nk)                                      \
        DN_STORE(BUF, P0, P1, R0, R1, R2, R3);                                  \
        if ((nk) < I_DIM) { DN_LOADB(R0, R1, R2, R3, (nk)); DN_LOADA(P0, P1, (nk)); } \
        LGKM0();                                                                \
        RAWBAR();                                                               \
        __builtin_amdgcn_s_setprio(1);                                          \
        DN_MFMA(BUF);                                                           \
        __builtin_amdgcn_s_setprio(0);

        DN_LOADB(bA0, bA1, bA2, bA3, 0);    DN_LOADA(aA0, aA1, 0);
        DN_LOADB(bB0, bB1, bB2, bB3, BKS);  DN_LOADA(aB0, aB1, BKS);

        for (int ii = 0; ii < I_DIM; ii += 2 * BKS) {
            DN_PHASE(0, aA0, aA1, bA0, bA1, bA2, bA3, ii + 2 * BKS);
            DN_PHASE(1, aB0, aB1, bB0, bB1, bB2, bB3, ii + 3 * BKS);
        }
        __syncthreads();
#undef DN_LOADA
#undef DN_LOADB
#undef DN_STORE
#undef DN_MFMA
#undef DN_PHASE

        if (mact) {
            #pragma unroll
            for (int mf = 0; mf < 4; ++mf)
                #pragma unroll
                for (int r = 0; r < 4; ++r) {
                    int pos = mstart + wm * 64 + mf * 16 + kb * 4 + r;
                    if (pos < count) {
                        if constexpr (USE_PART) {
                            part[(size_t)(off + pos) * H_DIM + h0 + wn * 16 + l15] =
                                f2bf(acc[mf][r]);
                        } else {
                            int tok = lists[e * NTOK + pos];
                            atomicAdd(&out[(size_t)tok * H_DIM + h0 + wn * 16 + l15],
                                      acc[mf][r]);
                        }
                    }
                }
        }
    }
}

// one block per token: sum its 8 partial rows (bf16) in fp32 -> out
__global__ __launch_bounds__(256) void reduce_kernel(
    const unsigned short* __restrict__ part,
    const int* __restrict__ topk_idx, const int* __restrict__ invmap,
    const int* __restrict__ offsets, float* __restrict__ out)
{
    const int t   = blockIdx.x;
    const int tid = threadIdx.x;
    __shared__ int slots[TOPK];
    if (tid < TOPK) {
        int s = t * TOPK + tid;
        slots[tid] = offsets[topk_idx[s]] + invmap[s];
    }
    __syncthreads();

    const int c = tid * 8;
    float acc[8] = {0.f, 0.f, 0.f, 0.f, 0.f, 0.f, 0.f, 0.f};
    #pragma unroll
    for (int k = 0; k < TOPK; ++k) {
        u16x8 v = *(const u16x8*)&part[(size_t)slots[k] * H_DIM + c];
        #pragma unroll
        for (int j = 0; j < 8; ++j)
            acc[j] += __uint_as_float((u32)(unsigned short)v[j] << 16);
    }
    float4* dst = (float4*)&out[(size_t)t * H_DIM + c];
    dst[0] = (float4){acc[0], acc[1], acc[2], acc[3]};
    dst[1] = (float4){acc[4], acc[5], acc[6], acc[7]};
}

extern "C" void kernel_launch(void* const* d_in, const int* in_sizes, int n_in,
                              void* d_out, int out_size, void* d_ws, size_t ws_size,
                              hipStream_t stream) {
    const float* x  = (const float*)d_in[0];
    const float* Wr = (const float*)d_in[1];
    const float* Wg = (const float*)d_in[2];
    const float* Wu = (const float*)d_in[3];
    const float* Wd = (const float*)d_in[4];
    float* out = (float*)d_out;

    char* ws = (char*)d_ws;
    int*   topk_idx = (int*)  (ws + 0);
    float* topk_w   = (float*)(ws + 32768);
    int*   counts   = (int*)  (ws + 65536);
    int*   offsets  = (int*)  (ws + 65792);
    int*   lists    = (int*)  (ws + 66048);
    float* wlist    = (float*)(ws + 328192);
    int*   invmap   = (int*)  (ws + 590336);
    unsigned short* hmid = (unsigned short*)(ws + 623104);
    unsigned short* xbf  = (unsigned short*)(ws + 13206016);
    unsigned short* part = (unsigned short*)(ws + 17400320);

    const bool usePart = ws_size >= WS_NEEDED;

    hipLaunchKernelGGL(router_kernel, dim3(NTOK), dim3(512), 0, stream,
                       x, Wr, topk_idx, topk_w, (ushort4*)xbf);
    hipLaunchKernelGGL(listbuild_kernel, dim3(NEXP), dim3(64), 0, stream,
                       topk_idx, topk_w, counts, lists, wlist, invmap);
    hipLaunchKernelGGL(scan_kernel, dim3(1), dim3(64), 0, stream,
                       counts, offsets);
    hipLaunchKernelGGL(gateup_kernel, dim3(24 * NEXP), dim3(512), 0, stream,
                       xbf, Wg, Wu, counts, offsets, lists, wlist, hmid);
    if (usePart) {
        hipLaunchKernelGGL((down_kernel<true>), dim3(64 * NEXP), dim3(512), 0, stream,
                           hmid, Wd, counts, offsets, lists, out, part);
        hipLaunchKernelGGL(reduce_kernel, dim3(NTOK), dim3(256), 0, stream,
                           part, topk_idx, invmap, offsets, out);
    } else {
        const int nout4 = NTOK * H_DIM / 4;
        hipLaunchKernelGGL(zero_kernel, dim3((nout4 + 255) / 256), dim3(256), 0, stream,
                           (float4*)out, nout4);
        hipLaunchKernelGGL((down_kernel<false>), dim3(64 * NEXP), dim3(512), 0, stream,
                           hmid, Wd, counts, offsets, lists, out, part);
    }
}

// Round 20
// 470.744 us; speedup vs baseline: 1.0162x; 1.0162x over previous
//
#include <hip/hip_runtime.h>
#include <hip/hip_bf16.h>

#define H_DIM 2048
#define I_DIM 768
#define NEXP 64
#define TOPK 8
#define NTOK 1024   // B*S
#define BM 256      // token tile (count ~128+-11 => single chunk)
#define BKS 32      // K per step

typedef float f32x4 __attribute__((ext_vector_type(4)));
typedef unsigned int u32x4 __attribute__((ext_vector_type(4)));
typedef unsigned int u32x2 __attribute__((ext_vector_type(2)));
typedef short bf16v8 __attribute__((ext_vector_type(8)));   // 8 bf16 in 4 VGPRs
typedef unsigned short u16x8 __attribute__((ext_vector_type(8)));
typedef unsigned int u32;

#define NTLOAD __builtin_nontemporal_load

// ---------------- workspace layout (bytes) ----------------
// topk_idx : int   [NTOK*TOPK]           @ 0
// topk_w   : float [NTOK*TOPK]           @ 32768
// counts   : int   [NEXP]                @ 65536
// offsets  : int   [NEXP]                @ 65792
// lists    : int   [NEXP*NTOK]           @ 66048    (ends 328192)
// wlist    : float [NEXP*NTOK]           @ 328192   (ends 590336)
// inv      : int   [NTOK*TOPK]           @ 590336   (ends 623104)
// hmid     : bf16  [NTOK*TOPK * I_DIM]   @ 623104   (ends 13206016)
// xbf      : bf16  [NTOK * H_DIM]        @ 13206016 (ends 17400320)
// part     : bf16  [NTOK*TOPK * H_DIM]   @ 17400320 (ends 50954752)
#define WS_NEEDED 50954752ull

__device__ inline unsigned short f2bf(float f) {
    union { float f; u32 u; } v; v.f = f;
    u32 r = (v.u + 0x7FFFu + ((v.u >> 16) & 1u)) >> 16;
    return (unsigned short)r;
}
__device__ inline u32 pack2(float a, float b) {
    return (u32)f2bf(a) | ((u32)f2bf(b) << 16);
}

__global__ void zero_kernel(float4* p, int n4) {
    int i = blockIdx.x * blockDim.x + threadIdx.x;
    if (i < n4) p[i] = (float4){0.f, 0.f, 0.f, 0.f};
}

// one block per token, 512 threads: fused x->bf16 conversion + 8-way-K router
__global__ __launch_bounds__(512) void router_kernel(
    const float* __restrict__ x, const float* __restrict__ Wr,
    int* __restrict__ topk_idx, float* __restrict__ topk_w,
    ushort4* __restrict__ xbf)
{
    const int t   = blockIdx.x;
    const int tid = threadIdx.x;
    const int lane = tid & 63;
    const int wv   = tid >> 6;           // 0..7 -> K chunk of 256
    __shared__ float xs[H_DIM];
    __shared__ float red[8][64];

    const float* xrow = x + (size_t)t * H_DIM;
    {
        const float4* src = (const float4*)xrow;
        float4 v = src[tid];             // 512 threads x float4 = 2048 floats
        ((float4*)xs)[tid] = v;
        ushort4 o;
        o.x = f2bf(v.x); o.y = f2bf(v.y); o.z = f2bf(v.z); o.w = f2bf(v.w);
        xbf[(size_t)t * (H_DIM / 4) + tid] = o;   // fused bf16 copy
    }
    __syncthreads();

    float acc = 0.f;
    const int h0 = wv * 256;
    #pragma unroll 8
    for (int h = h0; h < h0 + 256; ++h) acc += xs[h] * Wr[(size_t)h * NEXP + lane];
    red[wv][lane] = acc;
    __syncthreads();

    if (tid < 64) {
        const int e = tid;
        float logit = ((red[0][e] + red[1][e]) + (red[2][e] + red[3][e]))
                    + ((red[4][e] + red[5][e]) + (red[6][e] + red[7][e]));

        float m = logit;
        #pragma unroll
        for (int o = 32; o > 0; o >>= 1) m = fmaxf(m, __shfl_xor(m, o));
        float p = __expf(logit - m);
        float s = p;
        #pragma unroll
        for (int o = 32; o > 0; o >>= 1) s += __shfl_xor(s, o);
        float prob = p / s;

        float myp = prob;
        float kw[TOPK]; int kid[TOPK]; float wsum = 0.f;
        #pragma unroll
        for (int k = 0; k < TOPK; ++k) {
            float v = myp; int bi = e;
            #pragma unroll
            for (int o = 32; o > 0; o >>= 1) {
                float ov = __shfl_xor(v, o);
                int   oi = __shfl_xor(bi, o);
                if (ov > v || (ov == v && oi < bi)) { v = ov; bi = oi; }
            }
            kw[k] = v; kid[k] = bi; wsum += v;
            if (e == bi) myp = -1.f;
        }
        if (e == 0) {
            float inv = 1.f / wsum;
            #pragma unroll
            for (int k = 0; k < TOPK; ++k) {
                topk_idx[t * TOPK + k] = kid[k];
                topk_w[t * TOPK + k]   = kw[k] * inv;
            }
        }
    }
}

// one wave per expert; deterministic ordered compaction + inverse rank map
__global__ __launch_bounds__(64) void listbuild_kernel(
    const int* __restrict__ topk_idx, const float* __restrict__ topk_w,
    int* __restrict__ counts, int* __restrict__ lists, float* __restrict__ wlist,
    int* __restrict__ invmap)
{
    const int e = blockIdx.x;
    const int lane = threadIdx.x;
    int n = 0;
    for (int base = 0; base < NTOK * TOPK; base += 64) {
        int s = base + lane;
        int idx = topk_idx[s];
        bool match = (idx == e);
        unsigned long long mask = __ballot(match);
        int pre = __popcll(mask & ((1ull << lane) - 1ull));
        if (match) {
            lists[e * NTOK + n + pre] = s >> 3;
            wlist[e * NTOK + n + pre] = topk_w[s];
            invmap[s] = n + pre;
        }
        n += __popcll(mask);
    }
    if (lane == 0) counts[e] = n;
}

__global__ __launch_bounds__(64) void scan_kernel(
    const int* __restrict__ counts, int* __restrict__ offsets)
{
    int e = threadIdx.x;
    int v = counts[e];
    int xacc = v;
    #pragma unroll
    for (int o = 1; o < 64; o <<= 1) {
        int y = __shfl_up(xacc, o);
        if (e >= o) xacc += y;
    }
    offsets[e] = xacc - v;
}

#define MFMA_BF16 __builtin_amdgcn_mfma_f32_16x16x32_bf16
#define LGKM0()  asm volatile("s_waitcnt lgkmcnt(0)" ::: "memory")
#define RAWBAR() __builtin_amdgcn_s_barrier()

// ---------------- MFMA gate+up: grid 1536 (xcd-swizzled), block 512, BN=32 ----------------
// Best measured config (R18): LDS dbuf + raw barrier + counted vmcnt + setprio + NT weights
__global__ __launch_bounds__(512, 4) void gateup_kernel(
    const unsigned short* __restrict__ xbf,
    const float* __restrict__ Wg, const float* __restrict__ Wu,
    const int* __restrict__ counts, const int* __restrict__ offsets,
    const int* __restrict__ lists, const float* __restrict__ wlist,
    unsigned short* __restrict__ hmid)
{
    const int b  = blockIdx.x;
    const int wg = (b & 7) * 192 + (b >> 3);
    const int itile = wg % 24;
    const int e     = wg / 24;

    const int count = counts[e];
    if (count == 0) return;
    const int off = offsets[e];
    const int i0 = itile * 32;

    __shared__ unsigned short Alds[2][BM][40];   // 40960 B
    __shared__ u32 Bgl[2][32 * 20];              // 5120 B
    __shared__ u32 Bul[2][32 * 20];              // 5120 B

    const int tid  = threadIdx.x;
    const int lane = tid & 63;
    const int wid  = tid >> 6;
    const int wm   = wid >> 1, wn = wid & 1;
    const int kb   = lane >> 4;
    const int l15  = lane & 15;

    const int ar = tid >> 1;
    const int ah = (tid & 1) * 16;
    const int bnn  = tid & 31;
    const int bkq  = (tid >> 5) & 7;
    const int bmat = tid >> 8;
    const float* WB = (bmat ? Wu : Wg) + (size_t)e * H_DIM * I_DIM + i0 + bnn;
    const int key4w = 4 * ((bnn >> 3) & 3);
    const int bwoff = bnn * 20 + ((2 * bkq) ^ key4w);
    const int brn   = wn * 16 + l15;
    const int key4r = 4 * ((brn >> 3) & 3);

    for (int mstart = 0; mstart < count; mstart += BM) {
        const int pr = mstart + ar;
        const bool aact = pr < count;
        const unsigned short* xrow = xbf + (size_t)(aact ? lists[e * NTOK + pr] : 0) * H_DIM + ah;
        const bool mact = (mstart + wm * 64) < count;

        f32x4 accg[4], accu[4];
        #pragma unroll
        for (int i = 0; i < 4; ++i) {
            accg[i] = (f32x4){0.f, 0.f, 0.f, 0.f};
            accu[i] = (f32x4){0.f, 0.f, 0.f, 0.f};
        }

        u32x4 aA0, aA1, aB0, aB1;                 // A prefetch, 2 sets
        float bA0, bA1, bA2, bA3;                 // B prefetch set A
        float bB0, bB1, bB2, bB3;                 // B prefetch set B

#define GU_LOADA(P0,P1,h)                                                       \
        if (aact) {                                                             \
            const u32x4* pa_ = (const u32x4*)(xrow + (h));                      \
            P0 = pa_[0]; P1 = pa_[1];                                           \
        }
#define GU_LOADB(R0,R1,R2,R3,h)                                                 \
        {                                                                       \
            R0 = NTLOAD(WB + (size_t)((h) + 4 * bkq)     * I_DIM);              \
            R1 = NTLOAD(WB + (size_t)((h) + 4 * bkq + 1) * I_DIM);              \
            R2 = NTLOAD(WB + (size_t)((h) + 4 * bkq + 2) * I_DIM);              \
            R3 = NTLOAD(WB + (size_t)((h) + 4 * bkq + 3) * I_DIM);              \
        }
#define GU_STORE(BUF,P0,P1,R0,R1,R2,R3)                                         \
        if (aact) {                                                             \
            *(u32x4*)&Alds[BUF][ar][ah]     = P0;                               \
            *(u32x4*)&Alds[BUF][ar][ah + 8] = P1;                               \
        }                                                                       \
        {                                                                       \
            u32x2 w_; w_.x = pack2(R0, R1); w_.y = pack2(R2, R3);               \
            *(u32x2*)((bmat ? Bul[BUF] : Bgl[BUF]) + bwoff) = w_;               \
        }
#define GU_MFMA(BUF)                                                            \
        if (mact) {                                                             \
            bf16v8 af[4], bg, bu;                                               \
            _Pragma("unroll")                                                   \
            for (int mf = 0; mf < 4; ++mf)                                      \
                af[mf] = *(const bf16v8*)&Alds[BUF][wm * 64 + mf * 16 + l15][kb * 8]; \
            bg = *(const bf16v8*)&Bgl[BUF][brn * 20 + ((4 * kb) ^ key4r)];      \
            bu = *(const bf16v8*)&Bul[BUF][brn * 20 + ((4 * kb) ^ key4r)];      \
            _Pragma("unroll")                                                   \
            for (int mf = 0; mf < 4; ++mf) {                                    \
                accg[mf] = MFMA_BF16(af[mf], bg, accg[mf], 0, 0, 0);            \
                accu[mf] = MFMA_BF16(af[mf], bu, accu[mf], 0, 0, 0);            \
            }                                                                   \
        }
#define GU_PHASE(BUF,P0,P1,R0,R1,R2,R3,nh)                                      \
        GU_STORE(BUF, P0, P1, R0, R1, R2, R3);                                  \
        if ((nh) < H_DIM) { GU_LOADB(R0, R1, R2, R3, (nh)); GU_LOADA(P0, P1, (nh)); } \
        LGKM0();                                                                \
        RAWBAR();                                                               \
        __builtin_amdgcn_s_setprio(1);                                          \
        GU_MFMA(BUF);                                                           \
        __builtin_amdgcn_s_setprio(0);

        GU_LOADB(bA0, bA1, bA2, bA3, 0);    GU_LOADA(aA0, aA1, 0);
        GU_LOADB(bB0, bB1, bB2, bB3, BKS);  GU_LOADA(aB0, aB1, BKS);

        for (int hh = 0; hh < H_DIM; hh += 2 * BKS) {
            GU_PHASE(0, aA0, aA1, bA0, bA1, bA2, bA3, hh + 2 * BKS);
            GU_PHASE(1, aB0, aB1, bB0, bB1, bB2, bB3, hh + 3 * BKS);
        }
        __syncthreads();
#undef GU_LOADA
#undef GU_LOADB
#undef GU_STORE
#undef GU_MFMA
#undef GU_PHASE

        if (mact) {
            #pragma unroll
            for (int mf = 0; mf < 4; ++mf)
                #pragma unroll
                for (int r = 0; r < 4; ++r) {
                    int pos = mstart + wm * 64 + mf * 16 + kb * 4 + r;
                    if (pos < count) {
                        float wgt = wlist[e * NTOK + pos];
                        float g = accg[mf][r], u = accu[mf][r];
                        float s = 1.f / (1.f + __expf(-g));
                        hmid[(size_t)(off + pos) * I_DIM + i0 + wn * 16 + l15] = f2bf(g * s * u * wgt);
                    }
                }
        }
    }
}

// ---------------- MFMA down: grid 4096 (xcd-swizzled), block 512, BN=32 ----------------
template <bool USE_PART>
__global__ __launch_bounds__(512, 4) void down_kernel(
    const unsigned short* __restrict__ hmid, const float* __restrict__ Wd,
    const int* __restrict__ counts, const int* __restrict__ offsets,
    const int* __restrict__ lists, float* __restrict__ out,
    unsigned short* __restrict__ part)
{
    const int b  = blockIdx.x;
    const int wg = (b & 7) * 512 + (b >> 3);
    const int htile = wg % 64;
    const int e     = wg / 64;

    const int count = counts[e];
    if (count == 0) return;
    const int off = offsets[e];
    const int h0 = htile * 32;

    __shared__ unsigned short Alds[2][BM][40];   // 40960 B
    __shared__ u32 Bdl[2][32 * 20];              // 5120 B

    const int tid  = threadIdx.x;
    const int lane = tid & 63;
    const int wid  = tid >> 6;
    const int wm   = wid >> 1, wn = wid & 1;
    const int kb   = lane >> 4;
    const int l15  = lane & 15;

    const int ar = tid >> 1;
    const int ah = (tid & 1) * 16;
    const int bnn  = tid & 31;
    const int bkq  = (tid >> 5) & 7;
    const bool bact = tid < 256;
    const float* WB = Wd + (size_t)e * I_DIM * H_DIM + h0 + bnn;
    const int key4w = 4 * ((bnn >> 3) & 3);
    const int bwoff = bnn * 20 + ((2 * bkq) ^ key4w);
    const int brn   = wn * 16 + l15;
    const int key4r = 4 * ((brn >> 3) & 3);

    for (int mstart = 0; mstart < count; mstart += BM) {
        const int pr = mstart + ar;
        const bool aact = pr < count;
        const unsigned short* hrow = hmid + (size_t)(off + (aact ? pr : 0)) * I_DIM + ah;
        const bool mact = (mstart + wm * 64) < count;

        f32x4 acc[4];
        #pragma unroll
        for (int i = 0; i < 4; ++i) acc[i] = (f32x4){0.f, 0.f, 0.f, 0.f};

        u32x4 aA0, aA1, aB0, aB1;
        float bA0, bA1, bA2, bA3;
        float bB0, bB1, bB2, bB3;

#define DN_LOADA(P0,P1,k)                                                       \
        if (aact) {                                                             \
            const u32x4* p_ = (const u32x4*)(hrow + (k));                       \
            P0 = p_[0]; P1 = p_[1];                                             \
        }
#define DN_LOADB(R0,R1,R2,R3,k)                                                 \
        if (bact) {                                                             \
            R0 = NTLOAD(WB + (size_t)((k) + 4 * bkq)     * H_DIM);              \
            R1 = NTLOAD(WB + (size_t)((k) + 4 * bkq + 1) * H_DIM);              \
            R2 = NTLOAD(WB + (size_t)((k) + 4 * bkq + 2) * H_DIM);              \
            R3 = NTLOAD(WB + (size_t)((k) + 4 * bkq + 3) * H_DIM);              \
        }
#define DN_STORE(BUF,P0,P1,R0,R1,R2,R3)                                         \
        if (aact) {                                                             \
            *(u32x4*)&Alds[BUF][ar][ah]     = P0;                               \
            *(u32x4*)&Alds[BUF][ar][ah + 8] = P1;                               \
        }                                                                       \
        if (bact) {                                                             \
            u32x2 w_; w_.x = pack2(R0, R1); w_.y = pack2(R2, R3);               \
            *(u32x2*)(Bdl[BUF] + bwoff) = w_;                                   \
        }
#define DN_MFMA(BUF)                                                            \
        if (mact) {                                                             \
            bf16v8 af[4], bd;                                                   \
            _Pragma("unroll")                                                   \
            for (int mf = 0; mf < 4; ++mf)                                      \
                af[mf] = *(const bf16v8*)&Alds[BUF][wm * 64 + mf * 16 + l15][kb * 8]; \
            bd = *(const bf16v8*)&Bdl[BUF][brn * 20 + ((4 * kb) ^ key4r)];      \
            _Pragma("unroll")                                                   \
            for (int mf = 0; mf < 4; ++mf)                                      \
                acc[mf] = MFMA_BF16(af[mf], bd, acc[mf], 0, 0, 0);              \
        }
#define DN_PHASE(BUF,P0,P1,R0,R1,R2,R3,nk)                                      \
        DN_STORE(BUF, P0, P1, R0, R1, R2, R3);                                  \
        if ((nk) < I_DIM) { DN_LOADB(R0, R1, R2, R3, (nk)); DN_LOADA(P0, P1, (nk)); } \
        LGKM0();                                                                \
        RAWBAR();                                                               \
        __builtin_amdgcn_s_setprio(1);                                          \
        DN_MFMA(BUF);                                                           \
        __builtin_amdgcn_s_setprio(0);

        DN_LOADB(bA0, bA1, bA2, bA3, 0);    DN_LOADA(aA0, aA1, 0);
        DN_LOADB(bB0, bB1, bB2, bB3, BKS);  DN_LOADA(aB0, aB1, BKS);

        for (int ii = 0; ii < I_DIM; ii += 2 * BKS) {
            DN_PHASE(0, aA0, aA1, bA0, bA1, bA2, bA3, ii + 2 * BKS);
            DN_PHASE(1, aB0, aB1, bB0, bB1, bB2, bB3, ii + 3 * BKS);
        }
        __syncthreads();
#undef DN_LOADA
#undef DN_LOADB
#undef DN_STORE
#undef DN_MFMA
#undef DN_PHASE

        if (mact) {
            #pragma unroll
            for (int mf = 0; mf < 4; ++mf)
                #pragma unroll
                for (int r = 0; r < 4; ++r) {
                    int pos = mstart + wm * 64 + mf * 16 + kb * 4 + r;
                    if (pos < count) {
                        if constexpr (USE_PART) {
                            part[(size_t)(off + pos) * H_DIM + h0 + wn * 16 + l15] =
                                f2bf(acc[mf][r]);
                        } else {
                            int tok = lists[e * NTOK + pos];
                            atomicAdd(&out[(size_t)tok * H_DIM + h0 + wn * 16 + l15],
                                      acc[mf][r]);
                        }
                    }
                }
        }
    }
}

// one block per token: sum its 8 partial rows (bf16) in fp32 -> out
__global__ __launch_bounds__(256) void reduce_kernel(
    const unsigned short* __restrict__ part,
    const int* __restrict__ topk_idx, const int* __restrict__ invmap,
    const int* __restrict__ offsets, float* __restrict__ out)
{
    const int t   = blockIdx.x;
    const int tid = threadIdx.x;
    __shared__ int slots[TOPK];
    if (tid < TOPK) {
        int s = t * TOPK + tid;
        slots[tid] = offsets[topk_idx[s]] + invmap[s];
    }
    __syncthreads();

    const int c = tid * 8;
    float acc[8] = {0.f, 0.f, 0.f, 0.f, 0.f, 0.f, 0.f, 0.f};
    #pragma unroll
    for (int k = 0; k < TOPK; ++k) {
        u16x8 v = *(const u16x8*)&part[(size_t)slots[k] * H_DIM + c];
        #pragma unroll
        for (int j = 0; j < 8; ++j)
            acc[j] += __uint_as_float((u32)(unsigned short)v[j] << 16);
    }
    float4* dst = (float4*)&out[(size_t)t * H_DIM + c];
    dst[0] = (float4){acc[0], acc[1], acc[2], acc[3]};
    dst[1] = (float4){acc[4], acc[5], acc[6], acc[7]};
}

extern "C" void kernel_launch(void* const* d_in, const int* in_sizes, int n_in,
                              void* d_out, int out_size, void* d_ws, size_t ws_size,
                              hipStream_t stream) {
    const float* x  = (const float*)d_in[0];
    const float* Wr = (const float*)d_in[1];
    const float* Wg = (const float*)d_in[2];
    const float* Wu = (const float*)d_in[3];
    const float* Wd = (const float*)d_in[4];
    float* out = (float*)d_out;

    char* ws = (char*)d_ws;
    int*   topk_idx = (int*)  (ws + 0);
    float* topk_w   = (float*)(ws + 32768);
    int*   counts   = (int*)  (ws + 65536);
    int*   offsets  = (int*)  (ws + 65792);
    int*   lists    = (int*)  (ws + 66048);
    float* wlist    = (float*)(ws + 328192);
    int*   invmap   = (int*)  (ws + 590336);
    unsigned short* hmid = (unsigned short*)(ws + 623104);
    unsigned short* xbf  = (unsigned short*)(ws + 13206016);
    unsigned short* part = (unsigned short*)(ws + 17400320);

    const bool usePart = ws_size >= WS_NEEDED;

    hipLaunchKernelGGL(router_kernel, dim3(NTOK), dim3(512), 0, stream,
                       x, Wr, topk_idx, topk_w, (ushort4*)xbf);
    hipLaunchKernelGGL(listbuild_kernel, dim3(NEXP), dim3(64), 0, stream,
                       topk_idx, topk_w, counts, lists, wlist, invmap);
    hipLaunchKernelGGL(scan_kernel, dim3(1), dim3(64), 0, stream,
                       counts, offsets);
    hipLaunchKernelGGL(gateup_kernel, dim3(24 * NEXP), dim3(512), 0, stream,
                       xbf, Wg, Wu, counts, offsets, lists, wlist, hmid);
    if (usePart) {
        hipLaunchKernelGGL((down_kernel<true>), dim3(64 * NEXP), dim3(512), 0, stream,
                           hmid, Wd, counts, offsets, lists, out, part);
        hipLaunchKernelGGL(reduce_kernel, dim3(NTOK), dim3(256), 0, stream,
                           part, topk_idx, invmap, offsets, out);
    } else {
        const int nout4 = NTOK * H_DIM / 4;
        hipLaunchKernelGGL(zero_kernel, dim3((nout4 + 255) / 256), dim3(256), 0, stream,
                           (float4*)out, nout4);
        hipLaunchKernelGGL((down_kernel<false>), dim3(64 * NEXP), dim3(512), 0, stream,
                           hmid, Wd, counts, offsets, lists, out, part);
    }
}